// Round 1
// 763.464 us; speedup vs baseline: 1.0212x; 1.0212x over previous
//
#include <hip/hip_runtime.h>
#include <math.h>

// Problem constants
#define B_ROWS 8192
#define D_IN 1024
#define D_OUT 1024
#define NEXP 16
#define KDIM 8
// GEMM cols: 15*8 z-cols (0..119), 16*8 a-cols (120..247), pad to 256
#define NCOL 256

typedef __attribute__((ext_vector_type(8))) short bf16x8;   // 8 bf16 = 4 VGPRs
typedef __attribute__((ext_vector_type(4))) float f32x4;    // MFMA accumulator

// fp32 -> bf16 round-to-nearest-even (bit trick, finite inputs only)
__device__ __forceinline__ unsigned short f2bf_rne(float v) {
    unsigned u = __float_as_uint(v);
    u += 0x7fffu + ((u >> 16) & 1u);
    return (unsigned short)(u >> 16);
}
__device__ __forceinline__ float bf2f(unsigned short h) {
    return __uint_as_float(((unsigned)h) << 16);
}

// ---------------- K0: pack/transpose weights into WtT[col][d] ---------------
// One block per col (coalesced writes along d).
__global__ __launch_bounds__(256) void wt_pack_kernel(const float* __restrict__ Wz,
                                                      const float* __restrict__ Ww,
                                                      float* __restrict__ WtT) {
    const int c = blockIdx.x;  // 0..255
    for (int d = threadIdx.x; d < D_IN; d += 256) {
        float v = 0.0f;
        if (c < 120) {
            const int n = c >> 3, k = c & 7;
            v = Wz[n * (D_IN * KDIM) + d * KDIM + k];
        } else if (c < 248) {
            const int cc = c - 120;
            const int n = cc >> 3, k = cc & 7;
            v = Ww[n * (D_IN * KDIM) + d * KDIM + k];
        }
        WtT[c * D_IN + d] = v;
    }
}

// ---------------- K1: ZA = x @ Wt via split-bf16 MFMA -----------------------
// BM=64, BN=64, K-step 32. 256 threads = 4 waves; wave w computes rows
// [w*16, w*16+16) x all 64 cols as 4 16x16 MFMA tiles.
// Split trick: x = xh+xl, w = wh+wl (bf16 hi/lo); x*w ~= xh*wh + xh*wl + xl*wh.
// LDS is fragment-major: unit u = g*64 + lane (16B each) holds the exact 8 bf16
// lane needs -> ds_read_b128 at base + lane*16, conflict-free.
#define BM 64
#define BN 64
#define KB 32

__global__ __launch_bounds__(256) void gemm_kernel(const float* __restrict__ x,
                                                   const float* __restrict__ WtT,
                                                   float* __restrict__ ZA) {
    __shared__ bf16x8 XH[256], XL[256], WH[256], WL[256];  // 4 x 4KB = 16KB

    const int tid = threadIdx.x;
    const int wave = tid >> 6;      // 0..3 = row-group of 16
    const int lane = tid & 63;
    const int rowBase = blockIdx.x * BM;   // 0..8128
    const int colBase = blockIdx.y * BN;   // 0..192

    // staging: thread t loads 8 consecutive fp32 of row sRow, k-group sKg
    const int sRow = tid >> 2;      // 0..63 (x-tile row / w-tile col)
    const int sKg = tid & 3;        // 0..3  (k-group of 8)
    const float* xg = x + (size_t)(rowBase + sRow) * D_IN + sKg * 8;
    const float* wg = WtT + (size_t)(colBase + sRow) * D_IN + sKg * 8;
    // fragment-major LDS unit for this thread's 8 values
    const int sUnit = ((sRow >> 4) << 6) | (sKg << 4) | (sRow & 15);

    f32x4 acc[4];
#pragma unroll
    for (int ct = 0; ct < 4; ++ct)
#pragma unroll
        for (int q = 0; q < 4; ++q) acc[ct][q] = 0.0f;

    // prefetch chunk 0
    float4 px0 = *(const float4*)(xg + 0);
    float4 px1 = *(const float4*)(xg + 4);
    float4 pw0 = *(const float4*)(wg + 0);
    float4 pw1 = *(const float4*)(wg + 4);

    for (int kk = 0; kk < D_IN; kk += KB) {
        // convert current chunk to hi/lo bf16 and commit to LDS
        const float xv[8] = {px0.x, px0.y, px0.z, px0.w, px1.x, px1.y, px1.z, px1.w};
        const float wv[8] = {pw0.x, pw0.y, pw0.z, pw0.w, pw1.x, pw1.y, pw1.z, pw1.w};
        bf16x8 xh, xl, wh, wl;
#pragma unroll
        for (int i = 0; i < 8; ++i) {
            unsigned short h = f2bf_rne(xv[i]);
            xh[i] = (short)h;
            xl[i] = (short)f2bf_rne(xv[i] - bf2f(h));   // residual exact (Sterbenz)
            h = f2bf_rne(wv[i]);
            wh[i] = (short)h;
            wl[i] = (short)f2bf_rne(wv[i] - bf2f(h));
        }
        XH[sUnit] = xh; XL[sUnit] = xl; WH[sUnit] = wh; WL[sUnit] = wl;
        __syncthreads();

        // prefetch next chunk (hides global latency under MFMA section)
        if (kk + KB < D_IN) {
            px0 = *(const float4*)(xg + kk + KB);
            px1 = *(const float4*)(xg + kk + KB + 4);
            pw0 = *(const float4*)(wg + kk + KB);
            pw1 = *(const float4*)(wg + kk + KB + 4);
        }

        // A fragments for this wave's 16-row band (linear, conflict-free b128)
        const bf16x8 ah = XH[(wave << 6) | lane];
        const bf16x8 al = XL[(wave << 6) | lane];
#pragma unroll
        for (int ct = 0; ct < 4; ++ct) {
            const bf16x8 bh = WH[(ct << 6) | lane];
            const bf16x8 bl = WL[(ct << 6) | lane];
            acc[ct] = __builtin_amdgcn_mfma_f32_16x16x32_bf16(ah, bh, acc[ct], 0, 0, 0);
            acc[ct] = __builtin_amdgcn_mfma_f32_16x16x32_bf16(ah, bl, acc[ct], 0, 0, 0);
            acc[ct] = __builtin_amdgcn_mfma_f32_16x16x32_bf16(al, bh, acc[ct], 0, 0, 0);
        }
        __syncthreads();
    }

    // C/D layout (m89-verified): col = lane&15, row = (lane>>4)*4 + q
    const int cRow = rowBase + wave * 16 + ((lane >> 4) << 2);
    const int cCol = colBase + (lane & 15);
#pragma unroll
    for (int ct = 0; ct < 4; ++ct)
#pragma unroll
        for (int q = 0; q < 4; ++q)
            ZA[(size_t)(cRow + q) * NCOL + cCol + ct * 16] = acc[ct][q];
}

// ---------------- K2: per-row tree probs + softmax + permutation mix --------
// (unchanged from verified version)
__global__ __launch_bounds__(128) void gate_kernel(const float* __restrict__ ZA,
                                                   const float* __restrict__ bz,
                                                   const float* __restrict__ bw,
                                                   const float* __restrict__ perm,
                                                   float* __restrict__ wout) {
    __shared__ float red[128];
    __shared__ float u[128];

    const int b = blockIdx.x;
    const int tid = threadIdx.x;
    const int kk = tid >> 4;   // 0..7
    const int n = tid & 15;    // 0..15

    const float* za = ZA + b * NCOL;

    float prob = 1.0f;
#pragma unroll
    for (int L = 0; L < 4; ++L) {
        const int node = (1 << L) - 1 + (n >> (4 - L));
        const int bit = (n >> (3 - L)) & 1;
        const float v = za[node * 8 + kk] + bz[node * 8 + kk];
        float p;
        if (v <= -0.5f) p = 0.0f;
        else if (v >= 0.5f) p = 1.0f;
        else p = fmaf(-2.0f * v * v, v, fmaf(1.5f, v, 0.5f));
        prob *= bit ? (1.0f - p) : p;
    }

    const float a = za[120 + n * 8 + kk] + bw[n * 8 + kk];
    const float logit = (prob <= 0.0f) ? -3.4e38f : (a + logf(prob + 1e-8f));

    red[tid] = logit;
    __syncthreads();
#pragma unroll
    for (int s = 64; s > 0; s >>= 1) {
        if (tid < s) red[tid] = fmaxf(red[tid], red[tid + s]);
        __syncthreads();
    }
    const float mx = red[0];
    __syncthreads();

    u[tid] = expf(logit - mx);
    __syncthreads();

    const int l = tid & 15;
    const int chunk = tid >> 4;  // 0..7
    float partial = 0.0f;
#pragma unroll
    for (int e0 = 0; e0 < 16; ++e0) {
        const int e = chunk * 16 + e0;
        partial += u[e] * perm[(e >> 4) * 256 + (e & 15) * 16 + l];
    }
    red[tid] = partial;
    __syncthreads();
#pragma unroll
    for (int s = 64; s >= 16; s >>= 1) {
        if (tid < s) red[tid] += red[tid + s];
        __syncthreads();
    }
    if (tid < 16) {
        float tot = 0.0f;
#pragma unroll
        for (int l2 = 0; l2 < 16; ++l2) tot += red[l2];
        wout[b * NEXP + tid] = red[tid] / tot;
    }
}

// ---------------- K3: y[b,d] = sum_n f[b,d,n] * w[b,n] ----------------------
// (unchanged from verified version)
__global__ __launch_bounds__(256) void out_kernel(const float* __restrict__ f,
                                                  const float* __restrict__ w,
                                                  float* __restrict__ y) {
    __shared__ float ws_[16];
    const int b = blockIdx.x >> 2;                       // 0..8191
    const int d = ((blockIdx.x & 3) << 8) + threadIdx.x; // 0..1023
    if (threadIdx.x < 16) ws_[threadIdx.x] = w[b * NEXP + threadIdx.x];
    __syncthreads();

    const long idx = (long)b * D_OUT + d;
    const float4* f4 = (const float4*)(f + idx * NEXP);
    const float4 a0 = f4[0];
    const float4 a1 = f4[1];
    const float4 a2 = f4[2];
    const float4 a3 = f4[3];

    float r = a0.x * ws_[0] + a0.y * ws_[1] + a0.z * ws_[2] + a0.w * ws_[3]
            + a1.x * ws_[4] + a1.y * ws_[5] + a1.z * ws_[6] + a1.w * ws_[7]
            + a2.x * ws_[8] + a2.y * ws_[9] + a2.z * ws_[10] + a2.w * ws_[11]
            + a3.x * ws_[12] + a3.y * ws_[13] + a3.z * ws_[14] + a3.w * ws_[15];
    y[idx] = r;
}

// ---------------- launch ----------------------------------------------------
extern "C" void kernel_launch(void* const* d_in, const int* in_sizes, int n_in,
                              void* d_out, int out_size, void* d_ws, size_t ws_size,
                              hipStream_t stream) {
    const float* f = (const float*)d_in[0];     // (8192, 1024, 16)
    const float* x = (const float*)d_in[1];     // (8192, 1024)
    const float* perm = (const float*)d_in[2];  // (8, 16, 16)
    const float* Wz = (const float*)d_in[3];    // (15, 1024, 8)
    const float* bz = (const float*)d_in[4];    // (15, 8)
    const float* Ww = (const float*)d_in[5];    // (16, 1024, 8)
    const float* bw = (const float*)d_in[6];    // (16, 8)
    float* y = (float*)d_out;                   // (8192, 1024)

    // workspace layout
    float* WtT = (float*)d_ws;                   // 256*1024 = 262144 floats
    float* ZA = WtT + NCOL * D_IN;               // 8192*256 = 2097152 floats
    float* Wexp = ZA + (size_t)B_ROWS * NCOL;    // 8192*16  = 131072 floats

    // K0: pack weights transposed (col-major over d)
    wt_pack_kernel<<<dim3(NCOL), dim3(256), 0, stream>>>(Wz, Ww, WtT);
    // K1: gating GEMM via split-bf16 MFMA
    gemm_kernel<<<dim3(B_ROWS / BM, NCOL / BN), dim3(256), 0, stream>>>(x, WtT, ZA);
    // K2: tree + softmax + permutation mix
    gate_kernel<<<dim3(B_ROWS), dim3(128), 0, stream>>>(ZA, bz, bw, perm, Wexp);
    // K3: weighted expert sum
    out_kernel<<<dim3(B_ROWS * 4), dim3(256), 0, stream>>>(f, Wexp, y);
}

// Round 3
// 749.137 us; speedup vs baseline: 1.0407x; 1.0191x over previous
//
#include <hip/hip_runtime.h>
#include <math.h>

// Problem constants
#define B_ROWS 8192
#define D_IN 1024
#define D_OUT 1024
#define NEXP 16
#define NCOL 256   // 15*8 z-cols (0..119), 16*8 a-cols (120..247), pad to 256

typedef __attribute__((ext_vector_type(8))) short bf16x8;   // 8 bf16 = 4 VGPRs
typedef __attribute__((ext_vector_type(4))) float f32x4;    // MFMA accumulator

// fp32 -> bf16 round-to-nearest-even (bit trick, finite inputs only)
__device__ __forceinline__ unsigned short f2bf_rne(float v) {
    unsigned u = __float_as_uint(v);
    u += 0x7fffu + ((u >> 16) & 1u);
    return (unsigned short)(u >> 16);
}
__device__ __forceinline__ float bf2f(unsigned short h) {
    return __uint_as_float(((unsigned)h) << 16);
}

// ---------------- K0: pack W into fragment-major hi/lo bf16 -----------------
// Unit U = kc*1024 + cg*64 + kg*16 + c15 holds 8 bf16:
//   col = cg*16 + c15, d = kc*32 + kg*8 + e (e=0..7)
// so K1's wave reads unit base+lane as one coalesced global_load_dwordx4.
__global__ __launch_bounds__(256) void wpack_kernel(const float* __restrict__ Wz,
                                                    const float* __restrict__ Ww,
                                                    bf16x8* __restrict__ WH,
                                                    bf16x8* __restrict__ WL) {
    const int U = blockIdx.x * 256 + threadIdx.x;  // 0..32767
    const int c15 = U & 15;
    const int kg = (U >> 4) & 3;
    const int cg = (U >> 6) & 15;
    const int kc = U >> 10;            // 0..31
    const int col = cg * 16 + c15;
    const int d0 = kc * 32 + kg * 8;

    const float* src = nullptr;
    if (col < 120) {
        const int n = col >> 3, k = col & 7;
        src = Wz + n * (D_IN * 8) + k;
    } else if (col < 248) {
        const int c = col - 120;
        const int n = c >> 3, k = c & 7;
        src = Ww + n * (D_IN * 8) + k;
    }
    bf16x8 h, lo;
#pragma unroll
    for (int e = 0; e < 8; ++e) {
        const float v = src ? src[(d0 + e) * 8] : 0.0f;
        const unsigned short hh = f2bf_rne(v);
        h[e] = (short)hh;
        lo[e] = (short)f2bf_rne(v - bf2f(hh));   // residual exact (Sterbenz)
    }
    WH[U] = h;
    WL[U] = lo;
}

// ---------------- K1F: fused gating GEMM + tree + softmax + perm mix --------
// Grid 512 blocks x 256 thr. Block = 16 rows x all 256 cols.
// Wave w owns cols [w*64, w*64+64) as 4 16x16 tiles; BM=16 so all waves share
// the A fragment. B fragments come straight from the L2-hot fragment-major
// WH/WL tables (coalesced 16B/lane) -> NO barriers in the K-loop.
// Split-bf16: acc += ah*bh + ah*bl + al*bh (identical order to verified R1).
__global__ __launch_bounds__(256, 2) void fused_kernel(const float* __restrict__ x,
                                                       const bf16x8* __restrict__ WH,
                                                       const bf16x8* __restrict__ WL,
                                                       const float* __restrict__ perm,
                                                       const float* __restrict__ bz,
                                                       const float* __restrict__ bw,
                                                       float* __restrict__ wout) {
    __shared__ __align__(16) float ZAs[16][NCOL];   // 16 KB
    __shared__ float us[16][8][16];                 // 8 KB
    __shared__ __align__(16) float permS[8 * 256];  // 8 KB
    __shared__ float bzS[120];
    __shared__ float bwS[128];

    const int tid = threadIdx.x;
    const int w = tid >> 6;        // wave 0..3
    const int l = tid & 63;
    const int rowBase = blockIdx.x * 16;
    const int cgBase = w * 4;      // colgroups owned by this wave

    // stage perm/bz/bw (consumed only after the post-GEMM barrier)
    {
        const float4* p4 = (const float4*)perm;
        float4* s4 = (float4*)permS;
        s4[tid * 2 + 0] = p4[tid * 2 + 0];
        s4[tid * 2 + 1] = p4[tid * 2 + 1];
        if (tid < 120) bzS[tid] = bz[tid];
        if (tid < 128) bwS[tid] = bw[tid];
    }

    // A-side source: lane l covers row (l&15), k-octet (l>>4) of each 32-chunk
    const float* xg = x + (size_t)(rowBase + (l & 15)) * D_IN + ((l >> 4) << 3);

    f32x4 acc[4];
#pragma unroll
    for (int ct = 0; ct < 4; ++ct)
#pragma unroll
        for (int q = 0; q < 4; ++q) acc[ct][q] = 0.0f;

#pragma unroll 4
    for (int kc = 0; kc < 32; ++kc) {
        // B fragments: coalesced 16B/lane from L2-hot tables
        bf16x8 bh[4], bl[4];
#pragma unroll
        for (int ct = 0; ct < 4; ++ct) {
            const int u = (kc * 16 + cgBase + ct) * 64 + l;
            bh[ct] = WH[u];
            bl[ct] = WL[u];
        }
        // A fragment: 8 fp32 -> hi/lo bf16 (per-lane, L1-broadcast across waves)
        const float4 xa = *(const float4*)(xg + kc * 32);
        const float4 xb = *(const float4*)(xg + kc * 32 + 4);
        const float xv[8] = {xa.x, xa.y, xa.z, xa.w, xb.x, xb.y, xb.z, xb.w};
        bf16x8 ah, al;
#pragma unroll
        for (int i = 0; i < 8; ++i) {
            const unsigned short hh = f2bf_rne(xv[i]);
            ah[i] = (short)hh;
            al[i] = (short)f2bf_rne(xv[i] - bf2f(hh));
        }
#pragma unroll
        for (int ct = 0; ct < 4; ++ct) {
            acc[ct] = __builtin_amdgcn_mfma_f32_16x16x32_bf16(ah, bh[ct], acc[ct], 0, 0, 0);
            acc[ct] = __builtin_amdgcn_mfma_f32_16x16x32_bf16(ah, bl[ct], acc[ct], 0, 0, 0);
            acc[ct] = __builtin_amdgcn_mfma_f32_16x16x32_bf16(al, bh[ct], acc[ct], 0, 0, 0);
        }
    }

    // spill accumulators to LDS: row = (l>>4)*4+q, col = w*64 + ct*16 + (l&15)
    {
        const int r0 = (l >> 4) << 2;
        const int c0 = l & 15;
#pragma unroll
        for (int ct = 0; ct < 4; ++ct) {
            const int c = w * 64 + ct * 16 + c0;
#pragma unroll
            for (int q = 0; q < 4; ++q) ZAs[r0 + q][c] = acc[ct][q];
        }
    }
    __syncthreads();

    // ---- gate phase: thread (r = tid>>4, g = tid&15) ----
    const int r = tid >> 4;   // row within tile (16 rows x 16 lanes)
    const int g = tid & 15;   // phase A: leaf n; phase B: output l

    // phase A: logits for leaf n=g over all 8 tree-indices kk=j
    float logit[8];
#pragma unroll
    for (int j = 0; j < 8; ++j) {
        float prob = 1.0f;
#pragma unroll
        for (int L = 0; L < 4; ++L) {
            const int node = (1 << L) - 1 + (g >> (4 - L));
            const int bit = (g >> (3 - L)) & 1;
            const float v = ZAs[r][node * 8 + j] + bzS[node * 8 + j];
            float p;
            if (v <= -0.5f) p = 0.0f;
            else if (v >= 0.5f) p = 1.0f;
            else p = fmaf(-2.0f * v * v, v, fmaf(1.5f, v, 0.5f));
            prob *= bit ? (1.0f - p) : p;
        }
        const float a = ZAs[r][120 + g * 8 + j] + bwS[g * 8 + j];
        logit[j] = (prob <= 0.0f) ? -3.4e38f : (a + logf(prob + 1e-8f));
    }
    // row-wide max over 128 entries: 8 local + 16-lane butterfly
    float mx = logit[0];
#pragma unroll
    for (int j = 1; j < 8; ++j) mx = fmaxf(mx, logit[j]);
#pragma unroll
    for (int m = 1; m < 16; m <<= 1) mx = fmaxf(mx, __shfl_xor(mx, m));
#pragma unroll
    for (int j = 0; j < 8; ++j) us[r][j][g] = expf(logit[j] - mx);
    __syncthreads();

    // phase B: w~[l=g] = sum_{j,n} u[j,n] * perm[j][n][l]
    // us reads are 16-lane broadcasts; permS reads conflict-free (lanes = l)
    float wsum = 0.0f;
#pragma unroll
    for (int j = 0; j < 8; ++j)
#pragma unroll
        for (int n = 0; n < 16; ++n)
            wsum = fmaf(us[r][j][n], permS[j * 256 + n * 16 + g], wsum);

    float tot = wsum;
#pragma unroll
    for (int m = 1; m < 16; m <<= 1) tot += __shfl_xor(tot, m);
    wout[(rowBase + r) * NEXP + g] = wsum / tot;
}

// ---------------- K3: y[b,d] = sum_n f[b,d,n] * w[b,n] ----------------------
// (unchanged from verified version — HBM-bound at its floor)
__global__ __launch_bounds__(256) void out_kernel(const float* __restrict__ f,
                                                  const float* __restrict__ w,
                                                  float* __restrict__ y) {
    __shared__ float ws_[16];
    const int b = blockIdx.x >> 2;                       // 0..8191
    const int d = ((blockIdx.x & 3) << 8) + threadIdx.x; // 0..1023
    if (threadIdx.x < 16) ws_[threadIdx.x] = w[b * NEXP + threadIdx.x];
    __syncthreads();

    const long idx = (long)b * D_OUT + d;
    const float4* f4 = (const float4*)(f + idx * NEXP);
    const float4 a0 = f4[0];
    const float4 a1 = f4[1];
    const float4 a2 = f4[2];
    const float4 a3 = f4[3];

    float r = a0.x * ws_[0] + a0.y * ws_[1] + a0.z * ws_[2] + a0.w * ws_[3]
            + a1.x * ws_[4] + a1.y * ws_[5] + a1.z * ws_[6] + a1.w * ws_[7]
            + a2.x * ws_[8] + a2.y * ws_[9] + a2.z * ws_[10] + a2.w * ws_[11]
            + a3.x * ws_[12] + a3.y * ws_[13] + a3.z * ws_[14] + a3.w * ws_[15];
    y[idx] = r;
}

// ---------------- launch ----------------------------------------------------
extern "C" void kernel_launch(void* const* d_in, const int* in_sizes, int n_in,
                              void* d_out, int out_size, void* d_ws, size_t ws_size,
                              hipStream_t stream) {
    const float* f = (const float*)d_in[0];     // (8192, 1024, 16)
    const float* x = (const float*)d_in[1];     // (8192, 1024)
    const float* perm = (const float*)d_in[2];  // (8, 16, 16)
    const float* Wz = (const float*)d_in[3];    // (15, 1024, 8)
    const float* bz = (const float*)d_in[4];    // (15, 8)
    const float* Ww = (const float*)d_in[5];    // (16, 1024, 8)
    const float* bw = (const float*)d_in[6];    // (16, 8)
    float* y = (float*)d_out;                   // (8192, 1024)

    // workspace layout
    bf16x8* WH = (bf16x8*)d_ws;                  // 32768 units * 16B = 512 KB
    bf16x8* WL = WH + 32768;                     // 512 KB
    float* Wexp = (float*)(WL + 32768);          // 8192*16 floats

    // K0: fragment-major hi/lo bf16 weight pack
    wpack_kernel<<<dim3(128), dim3(256), 0, stream>>>(Wz, Ww, WH, WL);
    // K1F: fused gating GEMM + gate
    fused_kernel<<<dim3(B_ROWS / 16), dim3(256), 0, stream>>>(x, WH, WL, perm, bz, bw, Wexp);
    // K3: weighted expert sum
    out_kernel<<<dim3(B_ROWS * 4), dim3(256), 0, stream>>>(f, Wexp, y);
}